// Round 1
// baseline (531.951 us; speedup 1.0000x reference)
//
#include <hip/hip_runtime.h>
#include <math.h>

#define KS 63
#define PAD 31
#define SIGMA_F 32.0f
#define BB 8
#define CC 31
#define HH 512
#define WW 512

__device__ __forceinline__ int refl(int r, int n) {
    if (r < 0) r = -r;
    if (r >= n) r = 2 * n - 2 - r;
    return r;
}

// tmp layout: [16][512][512]  planes 0..7 = dx batches, 8..15 = dy batches
__global__ __launch_bounds__(256) void vblur_kernel(const float* __restrict__ dxn,
                                                    const float* __restrict__ dyn,
                                                    float* __restrict__ tmp) {
    __shared__ float sw[KS];
    int t = threadIdx.x;
    if (t < KS) sw[t] = expf(-(float)(t * t) * (1.0f / 2048.0f));
    __syncthreads();

    int blk = blockIdx.x;           // plane*512 + y
    int plane = blk >> 9;
    int y = blk & 511;
    const float* src = (plane < BB) ? (dxn + (size_t)plane * HH * WW)
                                    : (dyn + (size_t)(plane - BB) * HH * WW);
    float* dst = tmp + (size_t)blk * WW;

    for (int x = t; x < WW; x += 256) {
        float acc = 0.0f;
        #pragma unroll
        for (int i = 0; i < KS; ++i) {
            int ry = refl(y + i - PAD, HH);   // block-uniform -> scalarized
            acc += sw[i] * src[(size_t)ry * WW + x];
        }
        dst[x] = acc;
    }
}

__global__ __launch_bounds__(256) void hblur_kernel(const float* __restrict__ tmp,
                                                    float* __restrict__ blur,
                                                    float* __restrict__ partials) {
    __shared__ float sw[KS];
    __shared__ float row[WW];
    __shared__ float smax[4];
    int t = threadIdx.x;
    if (t < KS) sw[t] = expf(-(float)(t * t) * (1.0f / 2048.0f));

    int blk = blockIdx.x;           // plane*512 + y
    const float* src = tmp + (size_t)blk * WW;
    for (int x = t; x < WW; x += 256) row[x] = src[x];
    __syncthreads();

    float m = -INFINITY;
    float* dst = blur + (size_t)blk * WW;
    for (int x = t; x < WW; x += 256) {
        float acc = 0.0f;
        #pragma unroll
        for (int i = 0; i < KS; ++i) {
            acc += sw[i] * row[refl(x + i - PAD, WW)];
        }
        dst[x] = acc;
        m = fmaxf(m, acc);
    }
    // wave (64) reduce then cross-wave via LDS
    for (int off = 32; off; off >>= 1) m = fmaxf(m, __shfl_down(m, off, 64));
    if ((t & 63) == 0) smax[t >> 6] = m;
    __syncthreads();
    if (t == 0)
        partials[blk] = fmaxf(fmaxf(smax[0], smax[1]), fmaxf(smax[2], smax[3]));
}

__global__ __launch_bounds__(256) void reduce_max_kernel(const float* __restrict__ partials,
                                                         float* __restrict__ maxv) {
    int f = blockIdx.x;             // 0 = dx (blocks 0..4095), 1 = dy
    int t = threadIdx.x;
    float m = -INFINITY;
    for (int i = t; i < BB * HH; i += 256) m = fmaxf(m, partials[f * BB * HH + i]);
    __shared__ float smax[4];
    for (int off = 32; off; off >>= 1) m = fmaxf(m, __shfl_down(m, off, 64));
    if ((t & 63) == 0) smax[t >> 6] = m;
    __syncthreads();
    if (t == 0)
        maxv[f] = fmaxf(fmaxf(smax[0], smax[1]), fmaxf(smax[2], smax[3]));
}

__global__ __launch_bounds__(256) void warp_kernel(const float* __restrict__ xin,
                                                   const float* __restrict__ blur,
                                                   const float* __restrict__ maxv,
                                                   float* __restrict__ warped,
                                                   float* __restrict__ gridout) {
    int blk = blockIdx.x;           // b*512 + h
    int b = blk >> 9;
    int h = blk & 511;
    float sx = SIGMA_F / maxv[0];
    float sy = SIGMA_F / maxv[1];
    int t = threadIdx.x;

    const size_t plane = (size_t)HH * WW;
    const float* bdx = blur + (size_t)b * plane + (size_t)h * WW;
    const float* bdy = blur + (size_t)(BB + b) * plane + (size_t)h * WW;
    const float* xb = xin + (size_t)b * CC * plane;
    float* wout_base = warped + (size_t)b * CC * plane + (size_t)h * WW;

    for (int w = t; w < WW; w += 256) {
        float dx = bdx[w] * sx;
        float dy = bdy[w] * sy;
        float gpx = (float)w + dx;
        float gpy = (float)h + dy;
        float gnx = 2.0f * gpx / 511.0f - 1.0f;
        float gny = 2.0f * gpy / 511.0f - 1.0f;

        size_t gbase = ((((size_t)b * HH + h) * WW) + w) * 2;
        gridout[gbase]     = gnx;
        gridout[gbase + 1] = gny;

        float ix = (gnx + 1.0f) * 0.5f * 511.0f;
        float iy = (gny + 1.0f) * 0.5f * 511.0f;
        ix = fminf(fmaxf(ix, 0.0f), 511.0f);
        iy = fminf(fmaxf(iy, 0.0f), 511.0f);
        float x0f = floorf(ix), y0f = floorf(iy);
        float wx = ix - x0f,   wy = iy - y0f;
        int x0 = (int)x0f, y0 = (int)y0f;
        int x1 = min(x0 + 1, WW - 1), y1 = min(y0 + 1, HH - 1);
        float w00 = (1.0f - wx) * (1.0f - wy);
        float w01 = wx * (1.0f - wy);
        float w10 = (1.0f - wx) * wy;
        float w11 = wx * wy;
        size_t o00 = (size_t)y0 * WW + x0, o01 = (size_t)y0 * WW + x1;
        size_t o10 = (size_t)y1 * WW + x0, o11 = (size_t)y1 * WW + x1;

        float* wout = wout_base + w;
        #pragma unroll 4
        for (int c = 0; c < CC; ++c) {
            const float* xc = xb + (size_t)c * plane;
            float v = xc[o00] * w00 + xc[o01] * w01 + xc[o10] * w10 + xc[o11] * w11;
            wout[(size_t)c * plane] = v;
        }
    }
}

extern "C" void kernel_launch(void* const* d_in, const int* in_sizes, int n_in,
                              void* d_out, int out_size, void* d_ws, size_t ws_size,
                              hipStream_t stream) {
    const float* x   = (const float*)d_in[0];
    const float* dxn = (const float*)d_in[1];
    const float* dyn = (const float*)d_in[2];

    float* ws = (float*)d_ws;
    float* tmp      = ws;                       // 16*512*512 = 4,194,304 floats
    float* blur     = ws + 4194304;             // 4,194,304 floats
    float* partials = ws + 8388608;             // 8192 floats
    float* maxv     = ws + 8396800;             // 2 floats

    float* warped  = (float*)d_out;                       // 8*31*512*512
    float* gridout = (float*)d_out + (size_t)BB * CC * HH * WW;  // 8*512*512*2

    vblur_kernel<<<16 * HH, 256, 0, stream>>>(dxn, dyn, tmp);
    hblur_kernel<<<16 * HH, 256, 0, stream>>>(tmp, blur, partials);
    reduce_max_kernel<<<2, 256, 0, stream>>>(partials, maxv);
    warp_kernel<<<BB * HH, 256, 0, stream>>>(x, blur, maxv, warped, gridout);
}

// Round 2
// 346.529 us; speedup vs baseline: 1.5351x; 1.5351x over previous
//
#include <hip/hip_runtime.h>
#include <math.h>

#define SIGMA_F 32.0f
#define BB 8
#define CC 31
#define HH 512
#define WW 512
#define PLANE (HH * WW)

// ---- compile-time Gaussian weights: W[i] = exp(-i^2 / 2048), i in [0,63) ----
constexpr double cexp_neg(double t) {   // e^{-t}, t in [0, ~2]
    double u = -t / 16.0;
    double s = 1.0, term = 1.0;
    for (int k = 1; k < 14; ++k) { term *= u / (double)k; s += term; }
    s = s * s; s = s * s; s = s * s; s = s * s;   // ^16
    return s;
}
constexpr float gwf(int i) { return (float)cexp_neg((double)(i * i) / 2048.0); }

__device__ constexpr float W[64] = {
    gwf(0),  gwf(1),  gwf(2),  gwf(3),  gwf(4),  gwf(5),  gwf(6),  gwf(7),
    gwf(8),  gwf(9),  gwf(10), gwf(11), gwf(12), gwf(13), gwf(14), gwf(15),
    gwf(16), gwf(17), gwf(18), gwf(19), gwf(20), gwf(21), gwf(22), gwf(23),
    gwf(24), gwf(25), gwf(26), gwf(27), gwf(28), gwf(29), gwf(30), gwf(31),
    gwf(32), gwf(33), gwf(34), gwf(35), gwf(36), gwf(37), gwf(38), gwf(39),
    gwf(40), gwf(41), gwf(42), gwf(43), gwf(44), gwf(45), gwf(46), gwf(47),
    gwf(48), gwf(49), gwf(50), gwf(51), gwf(52), gwf(53), gwf(54), gwf(55),
    gwf(56), gwf(57), gwf(58), gwf(59), gwf(60), gwf(61), gwf(62), 0.0f
};

// Fused separable blur + per-block max.
// Grid: 16 planes x 32 bands of 16 rows. planes 0..7 = dx batches, 8..15 = dy.
// LDS vt[16][580]: vt[j][c] = vertical blur of (logical col c-31, row y0+j),
// halo cols via reflect so the horizontal pass is pure within-row.
__global__ __launch_bounds__(256, 2) void blur_fused_kernel(const float* __restrict__ dxn,
                                                            const float* __restrict__ dyn,
                                                            float* __restrict__ blur,
                                                            float* __restrict__ partials) {
    __shared__ __align__(16) float vt[16 * 580];
    __shared__ float smax[4];
    int t = threadIdx.x;
    int blk = blockIdx.x;
    int plane = blk >> 5;
    int band = blk & 31;
    int y0 = band << 4;
    const float* src = (plane < BB) ? dxn + (size_t)plane * PLANE
                                    : dyn + (size_t)(plane - BB) * PLANE;

    // ---- vertical pass: one column strip (16 rows) per task ----
    for (int c = t; c < 574; c += 256) {
        int L = c - 31;
        int scol = (L < 0) ? -L : ((L > HH - 1) ? 2 * HH - 2 - L : L);
        float acc[16];
        #pragma unroll
        for (int j = 0; j < 16; ++j) acc[j] = 0.0f;
        #pragma unroll
        for (int ro = 0; ro < 78; ++ro) {
            int rr = y0 - 31 + ro;
            int r = (rr < 0) ? -rr : ((rr > HH - 1) ? 2 * HH - 2 - rr : rr);
            float v = src[r * WW + scol];
            #pragma unroll
            for (int j = 0; j < 16; ++j) {
                int wi = ro - j;
                if (wi >= 0 && wi < 63) acc[j] += W[wi] * v;
            }
        }
        #pragma unroll
        for (int j = 0; j < 16; ++j) vt[j * 580 + c] = acc[j];
    }
    __syncthreads();

    // ---- horizontal pass: out[y][x] = sum_i W[i] * vt[y][x+i] ----
    float m = -INFINITY;
    int row = t & 15;
    int chunk0 = t >> 4;
    float* dstrow = blur + (size_t)plane * PLANE + (size_t)(y0 + row) * WW;
    const float* vrow = vt + row * 580;
    #pragma unroll
    for (int pass = 0; pass < 2; ++pass) {
        int x0 = (chunk0 + (pass << 4)) << 4;      // 0..496 step 16
        float acc[16];
        #pragma unroll
        for (int j = 0; j < 16; ++j) acc[j] = 0.0f;
        const float4* v4 = (const float4*)(vrow + x0);
        #pragma unroll
        for (int mi = 0; mi < 20; ++mi) {
            float4 vv = v4[mi];
            #pragma unroll
            for (int e = 0; e < 4; ++e) {
                float xv = (e == 0) ? vv.x : (e == 1) ? vv.y : (e == 2) ? vv.z : vv.w;
                int k = (mi << 2) + e;
                #pragma unroll
                for (int j = 0; j < 16; ++j) {
                    int wi = k - j;
                    if (wi >= 0 && wi < 63) acc[j] += W[wi] * xv;
                }
            }
        }
        #pragma unroll
        for (int j = 0; j < 16; ++j) m = fmaxf(m, acc[j]);
        float4* dst4 = (float4*)(dstrow + x0);
        #pragma unroll
        for (int q = 0; q < 4; ++q)
            dst4[q] = make_float4(acc[4 * q], acc[4 * q + 1], acc[4 * q + 2], acc[4 * q + 3]);
    }

    for (int off = 32; off; off >>= 1) m = fmaxf(m, __shfl_down(m, off, 64));
    if ((t & 63) == 0) smax[t >> 6] = m;
    __syncthreads();
    if (t == 0)
        partials[blk] = fmaxf(fmaxf(smax[0], smax[1]), fmaxf(smax[2], smax[3]));
}

__global__ __launch_bounds__(256) void reduce_max_kernel(const float* __restrict__ partials,
                                                         float* __restrict__ maxv) {
    int f = blockIdx.x;             // 0 = dx (entries 0..255), 1 = dy (256..511)
    int t = threadIdx.x;
    float m = partials[f * 256 + t];
    __shared__ float smax[4];
    for (int off = 32; off; off >>= 1) m = fmaxf(m, __shfl_down(m, off, 64));
    if ((t & 63) == 0) smax[t >> 6] = m;
    __syncthreads();
    if (t == 0)
        maxv[f] = fmaxf(fmaxf(smax[0], smax[1]), fmaxf(smax[2], smax[3]));
}

// Warp (grid-sample) kernel, channel-grouped + XCD-swizzled.
// Work id: wid = bcg*512 + h, bcg = cg*8 + b. Grid 16384 blocks; XCD k gets a
// contiguous 2048-wid chunk = 8 channels x 4 batches, sweeping h in order ->
// in-flight read footprint ~5 MB/XCD (L2-sized).
__global__ __launch_bounds__(256) void warp_kernel(const float* __restrict__ xin,
                                                   const float* __restrict__ blur,
                                                   const float* __restrict__ maxv,
                                                   float* __restrict__ warped,
                                                   float2* __restrict__ gridout) {
    int bid = blockIdx.x;
    int wid = (bid & 7) * 2048 + (bid >> 3);
    int h = wid & 511;
    int bcg = wid >> 9;            // 0..31
    int cg = bcg >> 3;             // 0..3
    int b = bcg & 7;
    int c0 = cg * 8;
    int t = threadIdx.x;

    float sx = SIGMA_F / maxv[0];
    float sy = SIGMA_F / maxv[1];

    const float* bdx = blur + (size_t)b * PLANE + (size_t)h * WW;
    const float* bdy = blur + (size_t)(BB + b) * PLANE + (size_t)h * WW;
    const float* xg = xin + (size_t)b * CC * PLANE + (size_t)c0 * PLANE;
    float* wout_base = warped + (size_t)b * CC * PLANE + (size_t)c0 * PLANE + (size_t)h * WW;

    #pragma unroll
    for (int ww = 0; ww < 2; ++ww) {
        int w = t + ww * 256;
        float dx = bdx[w] * sx;
        float dy = bdy[w] * sy;
        float gnx = 2.0f * ((float)w + dx) / 511.0f - 1.0f;
        float gny = 2.0f * ((float)h + dy) / 511.0f - 1.0f;

        if (cg == 0)
            gridout[((size_t)b * HH + h) * WW + w] = make_float2(gnx, gny);

        float ix = (gnx + 1.0f) * 0.5f * 511.0f;
        float iy = (gny + 1.0f) * 0.5f * 511.0f;
        ix = fminf(fmaxf(ix, 0.0f), 511.0f);
        iy = fminf(fmaxf(iy, 0.0f), 511.0f);
        float x0f = floorf(ix), y0f = floorf(iy);
        float wx = ix - x0f, wy = iy - y0f;
        int x0 = (int)x0f, y0 = (int)y0f;
        int x1 = min(x0 + 1, WW - 1), y1 = min(y0 + 1, HH - 1);
        float w00 = (1.0f - wx) * (1.0f - wy);
        float w01 = wx * (1.0f - wy);
        float w10 = (1.0f - wx) * wy;
        float w11 = wx * wy;
        size_t o00 = (size_t)y0 * WW + x0, o01 = (size_t)y0 * WW + x1;
        size_t o10 = (size_t)y1 * WW + x0, o11 = (size_t)y1 * WW + x1;

        float* wout = wout_base + w;
        if (cg < 3) {
            #pragma unroll
            for (int c = 0; c < 8; ++c) {
                const float* xc = xg + (size_t)c * PLANE;
                wout[(size_t)c * PLANE] =
                    xc[o00] * w00 + xc[o01] * w01 + xc[o10] * w10 + xc[o11] * w11;
            }
        } else {
            #pragma unroll
            for (int c = 0; c < 7; ++c) {
                const float* xc = xg + (size_t)c * PLANE;
                wout[(size_t)c * PLANE] =
                    xc[o00] * w00 + xc[o01] * w01 + xc[o10] * w10 + xc[o11] * w11;
            }
        }
    }
}

extern "C" void kernel_launch(void* const* d_in, const int* in_sizes, int n_in,
                              void* d_out, int out_size, void* d_ws, size_t ws_size,
                              hipStream_t stream) {
    const float* x   = (const float*)d_in[0];
    const float* dxn = (const float*)d_in[1];
    const float* dyn = (const float*)d_in[2];

    float* ws = (float*)d_ws;
    float* blur     = ws;                       // 16*512*512 = 4,194,304 floats
    float* partials = ws + 4194304;             // 512 floats
    float* maxv     = ws + 4194304 + 512;       // 2 floats

    float* warped   = (float*)d_out;                               // 8*31*512*512
    float2* gridout = (float2*)((float*)d_out + (size_t)BB * CC * PLANE);

    blur_fused_kernel<<<16 * 32, 256, 0, stream>>>(dxn, dyn, blur, partials);
    reduce_max_kernel<<<2, 256, 0, stream>>>(partials, maxv);
    warp_kernel<<<BB * 4 * HH, 256, 0, stream>>>(x, blur, maxv, warped, gridout);
}